// Round 1
// baseline (170.515 us; speedup 1.0000x reference)
//
#include <hip/hip_runtime.h>
#include <hip/hip_bf16.h>

#define N_NODES 25000
#define KFAN    32
#define FIN     256
#define FOUT    256

// round-to-nearest-even fp32 -> bf16 (no NaN handling needed here)
__device__ __forceinline__ ushort f2bf(float f) {
    unsigned int u = __float_as_uint(f);
    u += 0x7fffu + ((u >> 16) & 1u);
    return (ushort)(u >> 16);
}

// ---------------- Phase 1: y[j][o] = relu(x[j] @ W + b)  (bf16 out) --------
// 64x64 block tile, 256 threads as 16x16, each thread 4x4 micro-tile.
#define TM 64
#define TN 64
#define BK 32

__global__ __launch_bounds__(256) void gemm_relu_kernel(
    const float* __restrict__ x,     // [N_NODES][FIN]
    const float* __restrict__ W,     // [FIN][FOUT]
    const float* __restrict__ bias,  // [FOUT]
    ushort* __restrict__ y)          // [N_NODES][FOUT] bf16 bits
{
    __shared__ float xs[BK][TM + 4]; // k-major (transposed), stride 68 keeps 16B align
    __shared__ float ws[BK][TN];

    const int tid  = threadIdx.x;
    const int tm   = tid >> 4;   // 0..15 -> rows tm*4..tm*4+3
    const int tn   = tid & 15;   // 0..15 -> cols tn*4..tn*4+3
    const int row0 = blockIdx.x * TM;
    const int col0 = blockIdx.y * TN;

    float acc[4][4];
    #pragma unroll
    for (int i = 0; i < 4; ++i)
        #pragma unroll
        for (int j = 0; j < 4; ++j) acc[i][j] = 0.f;

    for (int kc = 0; kc < FIN; kc += BK) {
        // stage x chunk transposed: xs[k][m]  (64 rows x 32 k = 512 float4 granules)
        #pragma unroll
        for (int i = 0; i < 2; ++i) {
            int g   = i * 256 + tid;      // 0..511
            int r   = g >> 3;             // 0..63
            int kko = (g & 7) << 2;       // 0,4,...,28
            int gr  = row0 + r;
            float4 v = make_float4(0.f, 0.f, 0.f, 0.f);
            if (gr < N_NODES)
                v = *(const float4*)(x + (size_t)gr * FIN + kc + kko);
            xs[kko + 0][r] = v.x;
            xs[kko + 1][r] = v.y;
            xs[kko + 2][r] = v.z;
            xs[kko + 3][r] = v.w;
        }
        // stage W chunk: ws[k][n]  (32 k x 64 cols = 512 float4 granules)
        #pragma unroll
        for (int i = 0; i < 2; ++i) {
            int g  = i * 256 + tid;       // 0..511
            int kk = g >> 4;              // 0..31
            int c4 = g & 15;              // 0..15
            float4 v = *(const float4*)(W + (size_t)(kc + kk) * FOUT + col0 + c4 * 4);
            *(float4*)&ws[kk][c4 * 4] = v;
        }
        __syncthreads();

        #pragma unroll
        for (int k = 0; k < BK; ++k) {
            float4 a  = *(const float4*)&xs[k][tm * 4];
            float4 bb = *(const float4*)&ws[k][tn * 4];
            float av[4] = {a.x, a.y, a.z, a.w};
            float bv[4] = {bb.x, bb.y, bb.z, bb.w};
            #pragma unroll
            for (int i = 0; i < 4; ++i)
                #pragma unroll
                for (int j = 0; j < 4; ++j)
                    acc[i][j] = fmaf(av[i], bv[j], acc[i][j]);
        }
        __syncthreads();
    }

    // epilogue: +bias, relu, bf16 pack, 8B stores
    float bv[4];
    #pragma unroll
    for (int j = 0; j < 4; ++j) bv[j] = bias[col0 + tn * 4 + j];

    #pragma unroll
    for (int i = 0; i < 4; ++i) {
        int r = row0 + tm * 4 + i;
        if (r < N_NODES) {
            ushort4 pk;
            pk.x = f2bf(fmaxf(acc[i][0] + bv[0], 0.f));
            pk.y = f2bf(fmaxf(acc[i][1] + bv[1], 0.f));
            pk.z = f2bf(fmaxf(acc[i][2] + bv[2], 0.f));
            pk.w = f2bf(fmaxf(acc[i][3] + bv[3], 0.f));
            *(ushort4*)(y + (size_t)r * FOUT + col0 + tn * 4) = pk;
        }
    }
}

// ---------------- Phase 2: out[n][o] = max_k y[neigh[n][k]][o] -------------
// Half-wave (32 lanes) per node, 8 bf16 cols per lane (16B gather loads).
// 256 threads/block -> 8 nodes/block. Grid = 25000/8 = 3125 exactly.
__global__ __launch_bounds__(256) void pool_max_kernel(
    const ushort* __restrict__ y,    // [N_NODES][FOUT] bf16 bits
    const int* __restrict__ neigh,   // [N_NODES][KFAN]
    float* __restrict__ out)         // [N_NODES][FOUT]
{
    const int tid  = threadIdx.x;
    const int lane = tid & 63;
    const int wave = tid >> 6;
    const int half = lane >> 5;      // which node within the wave
    const int sl   = lane & 31;      // lane within half-wave
    const int n    = blockIdx.x * 8 + wave * 2 + half;
    const int col  = sl * 8;

    const int* nb = neigh + (size_t)n * KFAN;
    int idx[KFAN];
    #pragma unroll
    for (int k = 0; k < KFAN; ++k) idx[k] = nb[k];

    float acc[8];
    #pragma unroll
    for (int i = 0; i < 8; ++i) acc[i] = 0.f;  // relu output >= 0, so 0 is identity

    #pragma unroll 8
    for (int k = 0; k < KFAN; ++k) {
        const uint4 v = *(const uint4*)(y + (size_t)idx[k] * FOUT + col);
        acc[0] = fmaxf(acc[0], __uint_as_float(v.x << 16));
        acc[1] = fmaxf(acc[1], __uint_as_float(v.x & 0xffff0000u));
        acc[2] = fmaxf(acc[2], __uint_as_float(v.y << 16));
        acc[3] = fmaxf(acc[3], __uint_as_float(v.y & 0xffff0000u));
        acc[4] = fmaxf(acc[4], __uint_as_float(v.z << 16));
        acc[5] = fmaxf(acc[5], __uint_as_float(v.z & 0xffff0000u));
        acc[6] = fmaxf(acc[6], __uint_as_float(v.w << 16));
        acc[7] = fmaxf(acc[7], __uint_as_float(v.w & 0xffff0000u));
    }

    float* op = out + (size_t)n * FOUT + col;
    *(float4*)op       = make_float4(acc[0], acc[1], acc[2], acc[3]);
    *(float4*)(op + 4) = make_float4(acc[4], acc[5], acc[6], acc[7]);
}

extern "C" void kernel_launch(void* const* d_in, const int* in_sizes, int n_in,
                              void* d_out, int out_size, void* d_ws, size_t ws_size,
                              hipStream_t stream) {
    const float* x     = (const float*)d_in[0];
    const int*   neigh = (const int*)  d_in[1];
    const float* W     = (const float*)d_in[2];
    const float* bias  = (const float*)d_in[3];
    float*       out   = (float*)d_out;
    ushort*      y     = (ushort*)d_ws;   // 25000*256*2 = 12.8 MB scratch

    dim3 g1((N_NODES + TM - 1) / TM, FOUT / TN);   // (391, 4)
    gemm_relu_kernel<<<g1, 256, 0, stream>>>(x, W, bias, y);

    pool_max_kernel<<<N_NODES / 8, 256, 0, stream>>>(y, neigh, out);
}

// Round 3
// 127.685 us; speedup vs baseline: 1.3354x; 1.3354x over previous
//
#include <hip/hip_runtime.h>
#include <hip/hip_bf16.h>

#define N_NODES 25000
#define KFAN    32
#define FIN     256
#define FOUT    256

typedef float  f32x4  __attribute__((ext_vector_type(4)));
typedef short  s16x8  __attribute__((ext_vector_type(8)));
typedef short  s16x4  __attribute__((ext_vector_type(4)));

// round-to-nearest-even fp32 -> bf16 bits
__device__ __forceinline__ ushort f2bf(float f) {
    unsigned int u = __float_as_uint(f);
    u += 0x7fffu + ((u >> 16) & 1u);
    return (ushort)(u >> 16);
}
__device__ __forceinline__ unsigned int pack2(float a, float b) {
    return (unsigned int)f2bf(a) | ((unsigned int)f2bf(b) << 16);
}

// ---------------- Kernel 0: Wt[n][k] = bf16(W[k][n])  (256x256) ------------
__global__ __launch_bounds__(256) void transpose_w(
    const float* __restrict__ W, ushort* __restrict__ Wt)
{
    __shared__ float ls[32][33];
    const int bid = blockIdx.x;        // 64 blocks
    const int kt  = bid & 7;           // k-tile
    const int nt  = bid >> 3;          // n-tile
    const int t   = threadIdx.x;

    {
        int kl = t >> 3, n4 = (t & 7) * 4;
        float4 v = *(const float4*)(W + (size_t)(kt * 32 + kl) * FOUT + nt * 32 + n4);
        ls[kl][n4 + 0] = v.x; ls[kl][n4 + 1] = v.y;
        ls[kl][n4 + 2] = v.z; ls[kl][n4 + 3] = v.w;
    }
    __syncthreads();
    {
        int nl = t >> 3, k4 = (t & 7) * 4;
        ushort4 o;
        o.x = f2bf(ls[k4 + 0][nl]);
        o.y = f2bf(ls[k4 + 1][nl]);
        o.z = f2bf(ls[k4 + 2][nl]);
        o.w = f2bf(ls[k4 + 3][nl]);
        *(ushort4*)(Wt + (size_t)(nt * 32 + nl) * FIN + kt * 32 + k4) = o;
    }
}

// ---------------- Kernel 1: y = relu(x @ W + b) via MFMA bf16 --------------
// Block: 256 thr (4 waves), tile M=32 x N=256; wave w owns cols [w*64, w*64+64).
// Per wave: 2 row-tiles x 4 col-tiles of 16x16, mfma_f32_16x16x32_bf16.
// A staged in LDS (fp32->bf16 on the fly); B frags straight from L2-resident Wt.
__global__ __launch_bounds__(256) void gemm_mfma(
    const float*  __restrict__ x,     // [N][FIN] fp32
    const ushort* __restrict__ Wt,    // [FOUT][FIN] bf16 bits (W^T)
    const float*  __restrict__ bias,  // [FOUT]
    ushort*       __restrict__ y)     // [N][FOUT] bf16 bits
{
    __shared__ ushort As[32][72];     // rows 144B: 16B-aligned, 2-way-bank (free)

    const int tid  = threadIdx.x;
    const int lane = tid & 63;
    const int wv   = tid >> 6;
    const int l16  = lane & 15;
    const int q    = lane >> 4;       // quad 0..3
    const int row0 = blockIdx.x * 32;
    const int n0   = wv * 64;

    f32x4 acc[2][4];
    #pragma unroll
    for (int i = 0; i < 2; ++i)
        #pragma unroll
        for (int j = 0; j < 4; ++j) acc[i][j] = (f32x4)0.f;

    const int r    = tid >> 3;        // 0..31 staging row
    const int kcol = (tid & 7) * 8;   // 0..56 staging k offset

    for (int kc = 0; kc < FIN; kc += 64) {
        // stage A chunk (32 rows x 64 k) as bf16
        float4 v0 = make_float4(0.f, 0.f, 0.f, 0.f), v1 = v0;
        int gr = row0 + r;
        if (gr < N_NODES) {
            const float* p = x + (size_t)gr * FIN + kc + kcol;
            v0 = *(const float4*)p;
            v1 = *(const float4*)(p + 4);
        }
        uint4 pk;
        pk.x = pack2(v0.x, v0.y); pk.y = pack2(v0.z, v0.w);
        pk.z = pack2(v1.x, v1.y); pk.w = pack2(v1.z, v1.w);
        *(uint4*)&As[r][kcol] = pk;
        __syncthreads();

        #pragma unroll
        for (int kk = 0; kk < 64; kk += 32) {
            const int k0 = kk + q * 8;
            s16x8 a0 = *(const s16x8*)&As[l16][k0];
            s16x8 a1 = *(const s16x8*)&As[16 + l16][k0];
            #pragma unroll
            for (int ct = 0; ct < 4; ++ct) {
                const int n = n0 + ct * 16 + l16;
                s16x8 b = *(const s16x8*)(Wt + (size_t)n * FIN + kc + k0);
                acc[0][ct] = __builtin_amdgcn_mfma_f32_16x16x32_bf16(a0, b, acc[0][ct], 0, 0, 0);
                acc[1][ct] = __builtin_amdgcn_mfma_f32_16x16x32_bf16(a1, b, acc[1][ct], 0, 0, 0);
            }
        }
        __syncthreads();
    }

    // epilogue: +bias, relu, bf16 store.  D layout: col=lane&15, row=q*4+reg
    #pragma unroll
    for (int ct = 0; ct < 4; ++ct) {
        const int col = n0 + ct * 16 + l16;
        const float bv = bias[col];
        #pragma unroll
        for (int mt = 0; mt < 2; ++mt) {
            #pragma unroll
            for (int rr = 0; rr < 4; ++rr) {
                int row = row0 + mt * 16 + q * 4 + rr;
                if (row < N_NODES)
                    y[(size_t)row * FOUT + col] = f2bf(fmaxf(acc[mt][ct][rr] + bv, 0.f));
            }
        }
    }
}

// ---------------- Kernel 2: out[n][o] = max_k y[neigh[n][k]][o] ------------
// Column-chunked for XCD L2 locality: chunk = blockIdx%4 -> 64 cols -> the
// y slice per XCD is 25000*64*2B = 3.2MB < 4MB L2.  Packed i16-max on bf16
// bits (valid: relu => y >= 0 => IEEE order == integer order).
__global__ __launch_bounds__(256) void pool_max(
    const ushort* __restrict__ y,     // [N][FOUT] bf16 bits
    const int*    __restrict__ neigh, // [N][KFAN]
    float*        __restrict__ out)   // [N][FOUT] fp32
{
    const int bid   = blockIdx.x;
    const int chunk = bid & 3;        // 64-col chunk, pinned to XCD pair
    const int nb    = bid >> 2;
    const int tid   = threadIdx.x;
    const int lane  = tid & 63;
    const int g     = lane >> 4;      // group (node) within wave
    const int gl    = lane & 15;      // lane within group
    const int wv    = tid >> 6;

    const int n  = nb * 16 + wv * 4 + g;
    const int nc = n < N_NODES ? n : N_NODES - 1;

    // group's 32 neighbor indices: lane gl holds pair (2*gl, 2*gl+1)
    const int* np = neigh + (size_t)nc * KFAN + gl * 2;
    const int i0 = np[0], i1 = np[1];
    const int base16 = lane & 48;

    const ushort* yc = y + chunk * 64 + gl * 4;

    s16x4 acc = {0, 0, 0, 0};
    #pragma unroll
    for (int k = 0; k < KFAN; ++k) {
        int src = base16 | (k >> 1);
        int idx = __shfl((k & 1) ? i1 : i0, src);
        s16x4 cur = *(const s16x4*)(yc + (size_t)idx * FOUT);
        acc = __builtin_elementwise_max(acc, cur);
    }

    if (n < N_NODES) {
        f32x4 o;
        o.x = __uint_as_float(((unsigned int)(ushort)acc.x) << 16);
        o.y = __uint_as_float(((unsigned int)(ushort)acc.y) << 16);
        o.z = __uint_as_float(((unsigned int)(ushort)acc.z) << 16);
        o.w = __uint_as_float(((unsigned int)(ushort)acc.w) << 16);
        __builtin_nontemporal_store(o, (f32x4*)(out + (size_t)n * FOUT + chunk * 64 + gl * 4));
    }
}

extern "C" void kernel_launch(void* const* d_in, const int* in_sizes, int n_in,
                              void* d_out, int out_size, void* d_ws, size_t ws_size,
                              hipStream_t stream) {
    const float* x     = (const float*)d_in[0];
    const int*   neigh = (const int*)  d_in[1];
    const float* W     = (const float*)d_in[2];
    const float* bias  = (const float*)d_in[3];
    float*       out   = (float*)d_out;
    ushort*      y     = (ushort*)d_ws;    // 25000*256*2 = 12.8 MB
    // Park W^T (bf16, 128KB) at the front of d_out: gemm reads it, then
    // pool_max overwrites every element of d_out afterwards (stream-ordered).
    ushort*      Wt    = (ushort*)d_out;

    transpose_w<<<64, 256, 0, stream>>>(W, Wt);

    const int mblocks = (N_NODES + 31) / 32;               // 782
    gemm_mfma<<<mblocks, 256, 0, stream>>>(x, Wt, bias, y);

    const int nblocks = ((N_NODES + 15) / 16) * 4;         // 1563*4 = 6252
    pool_max<<<nblocks, 256, 0, stream>>>(y, neigh, out);
}

// Round 4
// 117.681 us; speedup vs baseline: 1.4490x; 1.0850x over previous
//
#include <hip/hip_runtime.h>
#include <hip/hip_bf16.h>

#define N_NODES 25000
#define KFAN    32
#define FIN     256
#define FOUT    256

typedef float  f32x4  __attribute__((ext_vector_type(4)));
typedef short  s16x8  __attribute__((ext_vector_type(8)));

// round-to-nearest-even fp32 -> bf16 bits
__device__ __forceinline__ ushort f2bf(float f) {
    unsigned int u = __float_as_uint(f);
    u += 0x7fffu + ((u >> 16) & 1u);
    return (ushort)(u >> 16);
}
__device__ __forceinline__ unsigned int pack2(float a, float b) {
    return (unsigned int)f2bf(a) | ((unsigned int)f2bf(b) << 16);
}

// ---------------- Kernel 0: Wt[n][k] = bf16(W[k][n])  (256x256) ------------
__global__ __launch_bounds__(256) void transpose_w(
    const float* __restrict__ W, ushort* __restrict__ Wt)
{
    __shared__ float ls[32][33];
    const int bid = blockIdx.x;        // 64 blocks
    const int kt  = bid & 7;           // k-tile
    const int nt  = bid >> 3;          // n-tile
    const int t   = threadIdx.x;

    {
        int kl = t >> 3, n4 = (t & 7) * 4;
        float4 v = *(const float4*)(W + (size_t)(kt * 32 + kl) * FOUT + nt * 32 + n4);
        ls[kl][n4 + 0] = v.x; ls[kl][n4 + 1] = v.y;
        ls[kl][n4 + 2] = v.z; ls[kl][n4 + 3] = v.w;
    }
    __syncthreads();
    {
        int nl = t >> 3, k4 = (t & 7) * 4;
        ushort4 o;
        o.x = f2bf(ls[k4 + 0][nl]);
        o.y = f2bf(ls[k4 + 1][nl]);
        o.z = f2bf(ls[k4 + 2][nl]);
        o.w = f2bf(ls[k4 + 3][nl]);
        *(ushort4*)(Wt + (size_t)(nt * 32 + nl) * FIN + kt * 32 + k4) = o;
    }
}

// ---------------- Kernel 1: y = relu(x @ W + b) via MFMA bf16 --------------
// Tile M=64 x N=128; block 256 thr (4 waves); wave wv owns 32 cols.
// Wave micro-tile: 4 (rows) x 2 (cols) of 16x16, mfma_f32_16x16x32_bf16.
// MFMA : B-load ratio 4:1 (vs 2:1 in the previous round).
__global__ __launch_bounds__(256) void gemm_mfma(
    const float*  __restrict__ x,     // [N][FIN] fp32
    const ushort* __restrict__ Wt,    // [FOUT][FIN] bf16 bits (W^T)
    const float*  __restrict__ bias,  // [FOUT]
    ushort*       __restrict__ y)     // [N][FOUT] bf16 bits
{
    __shared__ ushort As[64][72];     // 18 KB; rows 144B

    const int tid  = threadIdx.x;
    const int lane = tid & 63;
    const int wv   = tid >> 6;
    const int l16  = lane & 15;
    const int q    = lane >> 4;       // quad 0..3
    const int row0 = blockIdx.x * 64;
    const int n0   = blockIdx.y * 128 + wv * 32;

    f32x4 acc[4][2];
    #pragma unroll
    for (int i = 0; i < 4; ++i)
        #pragma unroll
        for (int j = 0; j < 2; ++j) acc[i][j] = (f32x4)0.f;

    const int r    = tid >> 2;        // 0..63 staging row
    const int kcol = (tid & 3) * 16;  // 0,16,32,48 staging k offset

    for (int kc = 0; kc < FIN; kc += 64) {
        // stage A chunk (64 rows x 64 k) as bf16; each thread 16 k of one row
        float4 v0 = make_float4(0.f,0.f,0.f,0.f), v1 = v0, v2 = v0, v3 = v0;
        int gr = row0 + r;
        if (gr < N_NODES) {
            const float* p = x + (size_t)gr * FIN + kc + kcol;
            v0 = *(const float4*)p;
            v1 = *(const float4*)(p + 4);
            v2 = *(const float4*)(p + 8);
            v3 = *(const float4*)(p + 12);
        }
        uint4 pa, pb;
        pa.x = pack2(v0.x, v0.y); pa.y = pack2(v0.z, v0.w);
        pa.z = pack2(v1.x, v1.y); pa.w = pack2(v1.z, v1.w);
        pb.x = pack2(v2.x, v2.y); pb.y = pack2(v2.z, v2.w);
        pb.z = pack2(v3.x, v3.y); pb.w = pack2(v3.z, v3.w);
        *(uint4*)&As[r][kcol]     = pa;
        *(uint4*)&As[r][kcol + 8] = pb;
        __syncthreads();

        #pragma unroll
        for (int kk = 0; kk < 64; kk += 32) {
            const int k0 = kk + q * 8;
            s16x8 a[4], b[2];
            #pragma unroll
            for (int mt = 0; mt < 4; ++mt)
                a[mt] = *(const s16x8*)&As[mt * 16 + l16][k0];
            #pragma unroll
            for (int ct = 0; ct < 2; ++ct)
                b[ct] = *(const s16x8*)(Wt + (size_t)(n0 + ct * 16 + l16) * FIN + kc + k0);
            #pragma unroll
            for (int mt = 0; mt < 4; ++mt)
                #pragma unroll
                for (int ct = 0; ct < 2; ++ct)
                    acc[mt][ct] = __builtin_amdgcn_mfma_f32_16x16x32_bf16(a[mt], b[ct], acc[mt][ct], 0, 0, 0);
        }
        __syncthreads();
    }

    // epilogue: +bias, relu, bf16 store.  D layout: col=lane&15, row=q*4+reg
    #pragma unroll
    for (int ct = 0; ct < 2; ++ct) {
        const int col = n0 + ct * 16 + l16;
        const float bv = bias[col];
        #pragma unroll
        for (int mt = 0; mt < 4; ++mt) {
            #pragma unroll
            for (int rr = 0; rr < 4; ++rr) {
                int row = row0 + mt * 16 + q * 4 + rr;
                if (row < N_NODES)
                    y[(size_t)row * FOUT + col] = f2bf(fmaxf(acc[mt][ct][rr] + bv, 0.f));
            }
        }
    }
}

// ---------------- Kernel 2: out[n][o] = max_k y[neigh[n][k]][o] ------------
// 64-col chunks pinned per-XCD (y slice 3.2MB < 4MB L2), 16B gather loads:
// 8 lanes per node-group, 8 nodes per wave, 32 nodes per block.
// Packed i16-max on bf16 bits (valid: relu => y >= 0).
__global__ __launch_bounds__(256) void pool_max(
    const ushort* __restrict__ y,     // [N][FOUT] bf16 bits
    const int*    __restrict__ neigh, // [N][KFAN]
    float*        __restrict__ out)   // [N][FOUT] fp32
{
    const int bid   = blockIdx.x;
    const int chunk = bid & 3;        // 64-col chunk, XCD-affine under %8 RR
    const int nb    = bid >> 2;
    const int tid   = threadIdx.x;
    const int lane  = tid & 63;
    const int g     = lane >> 3;      // node-group within wave (0..7)
    const int gl    = lane & 7;       // lane within group
    const int wv    = tid >> 6;

    const int n  = nb * 32 + wv * 8 + g;
    const int nc = n < N_NODES ? n : N_NODES - 1;

    // group's 32 neighbor indices: lane gl holds idx[4gl .. 4gl+3]
    const int4 iv = *(const int4*)(neigh + (size_t)nc * KFAN + gl * 4);
    const int base8 = lane & 56;
    int ia[4] = {iv.x, iv.y, iv.z, iv.w};

    const ushort* yc = y + chunk * 64 + gl * 8;

    s16x8 acc = (s16x8)0;
    #pragma unroll
    for (int k = 0; k < KFAN; ++k) {
        int idx = __shfl(ia[k & 3], base8 + (k >> 2));
        s16x8 cur = *(const s16x8*)(yc + (size_t)idx * FOUT);
        acc = __builtin_elementwise_max(acc, cur);
    }

    if (n < N_NODES) {
        f32x4 o0, o1;
        o0.x = __uint_as_float(((unsigned int)(ushort)acc[0]) << 16);
        o0.y = __uint_as_float(((unsigned int)(ushort)acc[1]) << 16);
        o0.z = __uint_as_float(((unsigned int)(ushort)acc[2]) << 16);
        o0.w = __uint_as_float(((unsigned int)(ushort)acc[3]) << 16);
        o1.x = __uint_as_float(((unsigned int)(ushort)acc[4]) << 16);
        o1.y = __uint_as_float(((unsigned int)(ushort)acc[5]) << 16);
        o1.z = __uint_as_float(((unsigned int)(ushort)acc[6]) << 16);
        o1.w = __uint_as_float(((unsigned int)(ushort)acc[7]) << 16);
        float* op = out + (size_t)n * FOUT + chunk * 64 + gl * 8;
        __builtin_nontemporal_store(o0, (f32x4*)op);
        __builtin_nontemporal_store(o1, (f32x4*)(op + 4));
    }
}

extern "C" void kernel_launch(void* const* d_in, const int* in_sizes, int n_in,
                              void* d_out, int out_size, void* d_ws, size_t ws_size,
                              hipStream_t stream) {
    const float* x     = (const float*)d_in[0];
    const int*   neigh = (const int*)  d_in[1];
    const float* W     = (const float*)d_in[2];
    const float* bias  = (const float*)d_in[3];
    float*       out   = (float*)d_out;
    ushort*      y     = (ushort*)d_ws;    // 12.8 MB of the 256 MiB ws
    // Park W^T (bf16, 128KB) at the front of d_out: gemm reads it, then
    // pool_max fully overwrites d_out afterwards (stream-ordered).
    ushort*      Wt    = (ushort*)d_out;

    transpose_w<<<64, 256, 0, stream>>>(W, Wt);

    dim3 g1((N_NODES + 63) / 64, 2);                       // (391, 2)
    gemm_mfma<<<g1, 256, 0, stream>>>(x, Wt, bias, y);

    const int nblocks = ((N_NODES + 31) / 32) * 4;         // 782*4 = 3128
    pool_max<<<nblocks, 256, 0, stream>>>(y, neigh, out);
}